// Round 4
// baseline (7497.131 us; speedup 1.0000x reference)
//
#include <hip/hip_runtime.h>
#include <stdint.h>
#include <stddef.h>

// ============================================================================
// RWKV block for MI355X. Round 4: ws_size-adaptive workspace (abort suspect:
// round-3 arena needed 994 MB of d_ws, never checked ws_size -> OOB abort).
//
// Footprint now: 726 MB (full-M) / 455 MB (2 batch chunks) / 320 MB (4 chunks),
// chosen at launch from ws_size (constant per session -> graph-safe).
//  - 4-slot lifetime plan; LN+mix runs once per branch into a shared slot.
//  - Wck/Wcv split into 3 K-chunks of 2048; partials accumulate into d_out.
//
// GEMMs: bf16 MFMA, 3-term hi/lo split (A*B ~= Ahi*Bhi + Alo*Bhi + Ahi*Blo,
// error ~ eps_bf16^2), m97 structure: 128x128 tile, BK=64, 4 waves, 16x16x32
// MFMA, global_load_lds(16B), B stored transposed [N,K] (ldb param), T1
// XCD-aware bijective swizzle (all grids have nwg % 8 == 0).
//
// WKV linear recurrence: 3-pass chunked scan (L=64), exact w^L carry.
// ============================================================================

typedef float  f32x4   __attribute__((ext_vector_type(4)));
typedef short  short8  __attribute__((ext_vector_type(8)));
typedef short  short4_ __attribute__((ext_vector_type(4)));
typedef __bf16 bf16x8  __attribute__((ext_vector_type(8)));

constexpr int kD   = 2048;
constexpr int kSeq = 4096;
constexpr int kBat = 4;
constexpr int kM   = kBat * kSeq;   // 16384 tokens
constexpr int kL   = 64;            // scan chunk length
constexpr int kC   = kSeq / kL;     // 64 chunks

// ---------------------------------------------------------------------------
// bf16 helpers (RNE)
// ---------------------------------------------------------------------------
__device__ __forceinline__ short f2bf(float f) {
  unsigned u = __builtin_bit_cast(unsigned, f);
  u += 0x7FFFu + ((u >> 16) & 1u);
  return (short)(u >> 16);
}
__device__ __forceinline__ float bf2f(short h) {
  unsigned u = ((unsigned)(unsigned short)h) << 16;
  return __builtin_bit_cast(float, u);
}
__device__ __forceinline__ void split_bf(float v, short& hi, short& lo) {
  hi = f2bf(v);
  lo = f2bf(v - bf2f(hi));
}

// ---------------------------------------------------------------------------
// block-wide reduction of 4 floats (256 threads = 4 waves), result broadcast
// ---------------------------------------------------------------------------
__device__ __forceinline__ f32x4 block_reduce4(f32x4 v) {
  #pragma unroll
  for (int off = 32; off > 0; off >>= 1) {
    v[0] += __shfl_down(v[0], off);
    v[1] += __shfl_down(v[1], off);
    v[2] += __shfl_down(v[2], off);
    v[3] += __shfl_down(v[3], off);
  }
  __shared__ float sh[4][4];
  const int wid = threadIdx.x >> 6, lane = threadIdx.x & 63;
  if (lane == 0) { sh[wid][0] = v[0]; sh[wid][1] = v[1]; sh[wid][2] = v[2]; sh[wid][3] = v[3]; }
  __syncthreads();
  #pragma unroll
  for (int i = 0; i < 4; ++i) v[i] = sh[0][i] + sh[1][i] + sh[2][i] + sh[3][i];
  return v;
}

// ---------------------------------------------------------------------------
// weight convert: fp32 W[K,N] -> bf16 hi/lo transposed [N,K]
// ---------------------------------------------------------------------------
__global__ __launch_bounds__(256) void wconvert_kernel(
    const float* __restrict__ W, short* __restrict__ hi, short* __restrict__ lo,
    int K, int N) {
  __shared__ float tile[32][33];
  const int tx = threadIdx.x & 31, ty = threadIdx.x >> 5;  // 32x8
  const int n0 = blockIdx.x * 32, k0 = blockIdx.y * 32;
  #pragma unroll
  for (int i = 0; i < 32; i += 8)
    tile[ty + i][tx] = W[(size_t)(k0 + ty + i) * N + (n0 + tx)];
  __syncthreads();
  #pragma unroll
  for (int i = 0; i < 32; i += 8) {
    float v = tile[tx][ty + i];           // = W[k0+tx][n0+ty+i]
    int n = n0 + ty + i, k = k0 + tx;
    short h, l; split_bf(v, h, l);
    hi[(size_t)n * K + k] = h;
    lo[(size_t)n * K + k] = l;
  }
}

// ---------------------------------------------------------------------------
// LayerNorm + token-shift blend for ONE coefficient vector, hi/lo output.
// One block per token row; recomputes LN of row s-1 in-block. Rows are
// chunk-local; chunks align to batch boundaries so s = row & (kSeq-1).
// ---------------------------------------------------------------------------
__global__ __launch_bounds__(256) void lnmix_kernel(
    const float* __restrict__ xb, const float* __restrict__ w, const float* __restrict__ b,
    const float* __restrict__ coeff,
    short* __restrict__ mhi, short* __restrict__ mlo) {
  const int row = blockIdx.x;
  const int s = row & (kSeq - 1);
  const float* xs = xb + (size_t)row * kD;
  const int t = threadIdx.x;
  f32x4 a[2];
  f32x4 p[2] = {};
  a[0] = *(const f32x4*)&xs[4 * t];
  a[1] = *(const f32x4*)&xs[1024 + 4 * t];
  if (s > 0) {
    p[0] = *(const f32x4*)&xs[4 * t - kD];
    p[1] = *(const f32x4*)&xs[1024 + 4 * t - kD];
  }
  f32x4 sums = {0.f, 0.f, 0.f, 0.f};
  #pragma unroll
  for (int g = 0; g < 2; ++g)
    #pragma unroll
    for (int j = 0; j < 4; ++j) {
      sums[0] += a[g][j]; sums[1] += a[g][j] * a[g][j];
      sums[2] += p[g][j]; sums[3] += p[g][j] * p[g][j];
    }
  sums = block_reduce4(sums);
  const float inv = 1.f / kD;
  const float ms = sums[0] * inv, vs = sums[1] * inv - ms * ms;
  const float mp = sums[2] * inv, vp = sums[3] * inv - mp * mp;
  const float rs = rsqrtf(vs + 1e-5f);
  const float rp = rsqrtf(vp + 1e-5f);
  #pragma unroll
  for (int g = 0; g < 2; ++g) {
    const int d0 = g * 1024 + 4 * t;
    short4_ mh, ml;
    #pragma unroll
    for (int j = 0; j < 4; ++j) {
      const int d = d0 + j;
      const float ww = w[d], bb = b[d];
      const float h  = (a[g][j] - ms) * rs * ww + bb;
      const float hp = (s > 0) ? (p[g][j] - mp) * rp * ww + bb : 0.f;
      const float c = coeff[d];
      short th, tl;
      split_bf(h * c + hp * (1.f - c), th, tl);
      mh[j] = th; ml[j] = tl;
    }
    const size_t o = (size_t)row * kD + d0;
    *(short4_*)&mhi[o] = mh; *(short4_*)&mlo[o] = ml;
  }
}

// ---------------------------------------------------------------------------
// WKV chunked scan over one batch-chunk (Bc batches of kSeq tokens).
// state_t = state_{t-1}*w + kv_t, w = exp(-exp(td)) per channel.
// ---------------------------------------------------------------------------
__global__ __launch_bounds__(256) void scan1_kernel(
    const float* __restrict__ kv, const float* __restrict__ td,
    float* __restrict__ chunk_end) {
  const int idx = blockIdx.x * 256 + threadIdx.x;          // (b_local,c,d)
  const int d = idx & (kD - 1);
  const int c = (idx >> 11) & (kC - 1);
  const int b = idx >> 17;
  const float w = expf(-expf(td[d]));
  const float* p = kv + ((size_t)b * kSeq + (size_t)c * kL) * kD + d;
  float st = 0.f;
  #pragma unroll 4
  for (int i = 0; i < kL; ++i) st = st * w + p[(size_t)i * kD];
  chunk_end[idx] = st;
}

__global__ __launch_bounds__(256) void scan2_kernel(
    const float* __restrict__ chunk_end, const float* __restrict__ td,
    float* __restrict__ carry) {
  const int idx = blockIdx.x * 256 + threadIdx.x;          // (b_local,d)
  const int d = idx & (kD - 1);
  const int b = idx >> 11;
  const float wL = expf(-expf(td[d]) * (float)kL);         // w^L exactly
  float c = 0.f;
  for (int i = 0; i < kC; ++i) {
    const size_t o = ((size_t)b * kC + i) * kD + d;
    carry[o] = c;
    c = c * wL + chunk_end[o];
  }
}

__global__ __launch_bounds__(256) void scan3_kernel(
    const float* __restrict__ kv, const float* __restrict__ carry,
    const float* __restrict__ rsig, const float* __restrict__ td,
    const float* __restrict__ tf,
    short* __restrict__ whi, short* __restrict__ wlo) {
  const int idx = blockIdx.x * 256 + threadIdx.x;          // (b_local,c,d)
  const int d = idx & (kD - 1);
  const int c = (idx >> 11) & (kC - 1);
  const int b = idx >> 17;
  const float w = expf(-expf(td[d]));
  float st = carry[idx];
  const size_t base = ((size_t)b * kSeq + (size_t)c * kL) * kD + d;
  const float bonus = (c == 0) ? expf(tf[d]) : 0.f;
  #pragma unroll 4
  for (int i = 0; i < kL; ++i) {
    const size_t o = base + (size_t)i * kD;
    const float kvv = kv[o];
    st = st * w + kvv;
    float out = rsig[o] * st;
    if (c == 0 && i == 0) out += rsig[o] * bonus * kvv;    // t==0 bonus
    short h, l; split_bf(out, h, l);
    whi[o] = h; wlo[o] = l;
  }
}

// ---------------------------------------------------------------------------
// 3-term split-bf16 GEMM, m97 structure + T1 XCD swizzle.
// A: row-major [M,K] (hi/lo, lda == K), B: transposed row-major [N-chunk, K]
// with row stride ldb (>= K). Logical K' = 3K via hi/lo pointer selection.
// ---------------------------------------------------------------------------
constexpr int EPI_SIG = 0, EPI_NONE = 1, EPI_MULK = 2, EPI_ADDX = 3,
              EPI_SQ = 4, EPI_ACC0 = 5, EPI_ACC1 = 6, EPI_FINAL = 7;

template <int EPI>
__global__ __launch_bounds__(256) void gemm3_kernel(
    const short* __restrict__ Ahi, const short* __restrict__ Alo,
    const short* __restrict__ Bhi, const short* __restrict__ Blo,
    int M, int N, int K, int ldb,
    float* __restrict__ outF,
    const float* __restrict__ aux1, const float* __restrict__ aux2,
    short* __restrict__ outHi, short* __restrict__ outLo) {
  __shared__ __align__(16) short As[128 * 64];
  __shared__ __align__(16) short Bs[128 * 64];
  const int tid = threadIdx.x;
  const int lane = tid & 63, wid = tid >> 6;
  const int wr = wid >> 1, wc = wid & 1;

  // T1: XCD-aware bijective swizzle (all grids here have nwg % 8 == 0).
  const int nwg = gridDim.x * gridDim.y;
  const int bid = blockIdx.y * gridDim.x + blockIdx.x;
  const int sw  = (bid & 7) * (nwg >> 3) + (bid >> 3);
  const int mBase = (sw / gridDim.x) * 128;
  const int nBase = (sw % gridDim.x) * 128;

  const int laneRow = lane >> 3;           // staging: 8 rows / 1KB chunk
  const int laneCol = (lane & 7) * 8;      // 8 bf16 = 16B per lane
  const int frow = lane & 15;              // MFMA fragment row/col
  const int fk = (lane >> 4) * 8;          // MFMA fragment k-offset
  const int ktiles = K >> 6;

  f32x4 acc[4][4] = {};

  for (int third = 0; third < 3; ++third) {
    const short* __restrict__ Ab = (third == 1) ? Alo : Ahi;
    const short* __restrict__ Bb = (third == 2) ? Blo : Bhi;
    for (int kt = 0; kt < ktiles; ++kt) {
      const int kk = kt << 6;
      __syncthreads();  // previous tile fully consumed before overwrite
      #pragma unroll
      for (int i = 0; i < 4; ++i) {
        const int chunk = wid * 4 + i;
        const int r = chunk * 8 + laneRow;
        const short* g = Ab + (size_t)(mBase + r) * K + (kk + laneCol);
        __builtin_amdgcn_global_load_lds(
            (const __attribute__((address_space(1))) void*)g,
            (__attribute__((address_space(3))) void*)(As + chunk * 512), 16, 0, 0);
      }
      #pragma unroll
      for (int i = 0; i < 4; ++i) {
        const int chunk = wid * 4 + i;
        const int r = chunk * 8 + laneRow;
        const short* g = Bb + (size_t)(nBase + r) * ldb + (kk + laneCol);
        __builtin_amdgcn_global_load_lds(
            (const __attribute__((address_space(1))) void*)g,
            (__attribute__((address_space(3))) void*)(Bs + chunk * 512), 16, 0, 0);
      }
      __syncthreads();  // staging complete (compiler drains vmcnt before barrier)
      #pragma unroll
      for (int ks = 0; ks < 2; ++ks) {
        const int kb = ks * 32 + fk;
        bf16x8 af[4], bfv[4];
        #pragma unroll
        for (int mi = 0; mi < 4; ++mi)
          af[mi] = __builtin_bit_cast(bf16x8,
              *(const short8*)&As[(wr * 64 + mi * 16 + frow) * 64 + kb]);
        #pragma unroll
        for (int ni = 0; ni < 4; ++ni)
          bfv[ni] = __builtin_bit_cast(bf16x8,
              *(const short8*)&Bs[(wc * 64 + ni * 16 + frow) * 64 + kb]);
        #pragma unroll
        for (int mi = 0; mi < 4; ++mi)
          #pragma unroll
          for (int ni = 0; ni < 4; ++ni)
            acc[mi][ni] = __builtin_amdgcn_mfma_f32_16x16x32_bf16(
                af[mi], bfv[ni], acc[mi][ni], 0, 0, 0);
      }
    }
  }

  // epilogue: D[row = (lane>>4)*4 + r, col = lane&15] per 16x16 fragment
  const int orow0 = (lane >> 4) * 4;
  const int ocol = lane & 15;
  #pragma unroll
  for (int mi = 0; mi < 4; ++mi) {
    #pragma unroll
    for (int ni = 0; ni < 4; ++ni) {
      const int gn = nBase + wc * 64 + ni * 16 + ocol;
      #pragma unroll
      for (int r = 0; r < 4; ++r) {
        const int gm = mBase + wr * 64 + mi * 16 + orow0 + r;
        const size_t idx = (size_t)gm * N + gn;
        const float v = acc[mi][ni][r];
        if constexpr (EPI == EPI_SIG) {
          outF[idx] = 1.f / (1.f + expf(-v));
        } else if constexpr (EPI == EPI_NONE) {
          outF[idx] = v;
        } else if constexpr (EPI == EPI_MULK) {
          outF[idx] = v * aux1[idx];
        } else if constexpr (EPI == EPI_ADDX) {
          outF[idx] = v + aux1[idx];
        } else if constexpr (EPI == EPI_SQ) {
          const float q = v * v;  // relu(square(z)) == z^2
          short h, l; split_bf(q, h, l);
          outHi[idx] = h; outLo[idx] = l;
        } else if constexpr (EPI == EPI_ACC0) {
          outF[idx] = v;                       // first K-chunk of Wcv
        } else if constexpr (EPI == EPI_ACC1) {
          outF[idx] += v;                      // middle K-chunk
        } else {  // EPI_FINAL: last K-chunk, full channel-mix epilogue
          outF[idx] = aux1[idx] + aux2[idx] * (outF[idx] + v);
        }
      }
    }
  }
}

// ---------------------------------------------------------------------------
// launch
// ---------------------------------------------------------------------------
extern "C" void kernel_launch(void* const* d_in, const int* in_sizes, int n_in,
                              void* d_out, int out_size, void* d_ws, size_t ws_size,
                              hipStream_t stream) {
  const float* x   = (const float*)d_in[0];
  const float* n1w = (const float*)d_in[1];
  const float* n1b = (const float*)d_in[2];
  const float* n2w = (const float*)d_in[3];
  const float* n2b = (const float*)d_in[4];
  const float* td  = (const float*)d_in[5];
  const float* tf  = (const float*)d_in[6];
  const float* Wr  = (const float*)d_in[7];
  const float* Wk  = (const float*)d_in[8];
  const float* Wv  = (const float*)d_in[9];
  const float* Wo  = (const float*)d_in[10];
  const float* tmr = (const float*)d_in[11];
  const float* tmk = (const float*)d_in[12];
  const float* tmv = (const float*)d_in[13];
  const float* Wcr = (const float*)d_in[14];
  const float* Wck = (const float*)d_in[15];
  const float* Wcv = (const float*)d_in[16];
  const float* cm  = (const float*)d_in[17];
  float* out = (float*)d_out;

  const size_t D2 = (size_t)kD * kD;            // 4,194,304 elems
  const size_t D3 = (size_t)kD * (3 * kD);      // 12,582,912 elems
  const size_t wbytes = (10 * D2 + 4 * D3) * sizeof(short);  // 184,549,376 B

  // choose batch-chunk count from ws_size (constant per session -> graph-safe)
  auto need = [&](int nc_) -> size_t {
    const size_t Mc_ = (size_t)kM / nc_;
    const size_t scanb = 2 * ((size_t)(kBat / nc_) * kC * kD) * sizeof(float);
    return wbytes + scanb + 4 * (Mc_ * kD * sizeof(float));
  };
  int nc = 4;
  if (ws_size >= need(1)) nc = 1;
  else if (ws_size >= need(2)) nc = 2;

  const size_t Mc = (size_t)kM / nc;  // tokens per chunk (multiple of kSeq)
  const int Bc = kBat / nc;           // batches per chunk

  // ---- workspace arena ----
  short* wp = (short*)d_ws;
  short* WrT_hi  = wp; wp += D2;  short* WrT_lo  = wp; wp += D2;
  short* WkT_hi  = wp; wp += D2;  short* WkT_lo  = wp; wp += D2;
  short* WvT_hi  = wp; wp += D2;  short* WvT_lo  = wp; wp += D2;
  short* WoT_hi  = wp; wp += D2;  short* WoT_lo  = wp; wp += D2;
  short* WcrT_hi = wp; wp += D2;  short* WcrT_lo = wp; wp += D2;
  short* WckT_hi = wp; wp += D3;  short* WckT_lo = wp; wp += D3;
  short* WcvT_hi = wp; wp += D3;  short* WcvT_lo = wp; wp += D3;
  float* chunk_end = (float*)wp;                       // Bc*kC*kD floats
  float* carry = chunk_end + (size_t)Bc * kC * kD;
  float* slotA = carry + (size_t)Bc * kC * kD;         // 4 slots, Mc*kD f32 each
  float* slotB = slotA + Mc * kD;
  float* slotC = slotB + Mc * kD;
  float* slotD = slotC + Mc * kD;

  const dim3 blk(256);

  // 1) weight conversion (once; ws re-poisoned by harness each timed call)
  wconvert_kernel<<<dim3(kD / 32, kD / 32), blk, 0, stream>>>(Wr,  WrT_hi,  WrT_lo,  kD, kD);
  wconvert_kernel<<<dim3(kD / 32, kD / 32), blk, 0, stream>>>(Wk,  WkT_hi,  WkT_lo,  kD, kD);
  wconvert_kernel<<<dim3(kD / 32, kD / 32), blk, 0, stream>>>(Wv,  WvT_hi,  WvT_lo,  kD, kD);
  wconvert_kernel<<<dim3(kD / 32, kD / 32), blk, 0, stream>>>(Wo,  WoT_hi,  WoT_lo,  kD, kD);
  wconvert_kernel<<<dim3(kD / 32, kD / 32), blk, 0, stream>>>(Wcr, WcrT_hi, WcrT_lo, kD, kD);
  wconvert_kernel<<<dim3(3 * kD / 32, kD / 32), blk, 0, stream>>>(Wck, WckT_hi, WckT_lo, kD, 3 * kD);
  wconvert_kernel<<<dim3(kD / 32, 3 * kD / 32), blk, 0, stream>>>(Wcv, WcvT_hi, WcvT_lo, 3 * kD, kD);

  for (int c = 0; c < nc; ++c) {
    const float* xc = x + (size_t)c * Mc * kD;
    float* outc = out + (size_t)c * Mc * kD;

    short* mbuf_hi = (short*)slotA; short* mbuf_lo = mbuf_hi + Mc * kD;
    float* r_sig = slotB;
    float* kbuf  = slotC;
    float* kvbuf = slotD;
    short* wkv_hi = (short*)slotC; short* wkv_lo = wkv_hi + Mc * kD;  // kbuf dead
    float* x1 = slotA;                                                // mbuf dead
    short* m2_hi = (short*)slotB; short* m2_lo = m2_hi + Mc * kD;     // r_sig dead
    float* r_cm = slotC;                                              // wkv dead
    short* kcm_hi = (short*)slotD; short* kcm_lo = kcm_hi + Mc * kD;  // kvbuf dead

    const dim3 gD(kD / 128, Mc / 128);   // D-wide GEMM grid

    // 2) time-mixing: r branch
    lnmix_kernel<<<Mc, blk, 0, stream>>>(xc, n1w, n1b, tmr, mbuf_hi, mbuf_lo);
    gemm3_kernel<EPI_SIG><<<gD, blk, 0, stream>>>(
        mbuf_hi, mbuf_lo, WrT_hi, WrT_lo, (int)Mc, kD, kD, kD,
        r_sig, nullptr, nullptr, nullptr, nullptr);
    // k branch
    lnmix_kernel<<<Mc, blk, 0, stream>>>(xc, n1w, n1b, tmk, mbuf_hi, mbuf_lo);
    gemm3_kernel<EPI_NONE><<<gD, blk, 0, stream>>>(
        mbuf_hi, mbuf_lo, WkT_hi, WkT_lo, (int)Mc, kD, kD, kD,
        kbuf, nullptr, nullptr, nullptr, nullptr);
    // v branch (fused *k -> kv)
    lnmix_kernel<<<Mc, blk, 0, stream>>>(xc, n1w, n1b, tmv, mbuf_hi, mbuf_lo);
    gemm3_kernel<EPI_MULK><<<gD, blk, 0, stream>>>(
        mbuf_hi, mbuf_lo, WvT_hi, WvT_lo, (int)Mc, kD, kD, kD,
        kvbuf, kbuf, nullptr, nullptr, nullptr);

    // 3) WKV scan (fused sigmoid(r)*state, t==0 bonus, bf16 split)
    scan1_kernel<<<(Bc * kC * kD) / 256, blk, 0, stream>>>(kvbuf, td, chunk_end);
    scan2_kernel<<<(Bc * kD) / 256, blk, 0, stream>>>(chunk_end, td, carry);
    scan3_kernel<<<(Bc * kC * kD) / 256, blk, 0, stream>>>(kvbuf, carry, r_sig, td, tf,
                                                           wkv_hi, wkv_lo);

    // 4) output projection + residual
    gemm3_kernel<EPI_ADDX><<<gD, blk, 0, stream>>>(
        wkv_hi, wkv_lo, WoT_hi, WoT_lo, (int)Mc, kD, kD, kD,
        x1, xc, nullptr, nullptr, nullptr);

    // 5) channel mixing
    lnmix_kernel<<<Mc, blk, 0, stream>>>(x1, n2w, n2b, cm, m2_hi, m2_lo);
    gemm3_kernel<EPI_SIG><<<gD, blk, 0, stream>>>(
        m2_hi, m2_lo, WcrT_hi, WcrT_lo, (int)Mc, kD, kD, kD,
        r_cm, nullptr, nullptr, nullptr, nullptr);

    // Wck/Wcv in 3 K-chunks of 2048; partials accumulate into outc
    for (int j = 0; j < 3; ++j) {
      gemm3_kernel<EPI_SQ><<<gD, blk, 0, stream>>>(
          m2_hi, m2_lo, WckT_hi + (size_t)j * kD * kD, WckT_lo + (size_t)j * kD * kD,
          (int)Mc, kD, kD, kD, nullptr, nullptr, nullptr, kcm_hi, kcm_lo);
      if (j == 0)
        gemm3_kernel<EPI_ACC0><<<gD, blk, 0, stream>>>(
            kcm_hi, kcm_lo, WcvT_hi + (size_t)j * kD, WcvT_lo + (size_t)j * kD,
            (int)Mc, kD, kD, 3 * kD, outc, nullptr, nullptr, nullptr, nullptr);
      else if (j == 1)
        gemm3_kernel<EPI_ACC1><<<gD, blk, 0, stream>>>(
            kcm_hi, kcm_lo, WcvT_hi + (size_t)j * kD, WcvT_lo + (size_t)j * kD,
            (int)Mc, kD, kD, 3 * kD, outc, nullptr, nullptr, nullptr, nullptr);
      else
        gemm3_kernel<EPI_FINAL><<<gD, blk, 0, stream>>>(
            kcm_hi, kcm_lo, WcvT_hi + (size_t)j * kD, WcvT_lo + (size_t)j * kD,
            (int)Mc, kD, kD, 3 * kD, outc, x1, r_cm, nullptr, nullptr);
    }
  }
}

// Round 5
// 5971.387 us; speedup vs baseline: 1.2555x; 1.2555x over previous
//
#include <hip/hip_runtime.h>
#include <stdint.h>
#include <stddef.h>

// ============================================================================
// RWKV block for MI355X. Round 5: GEMM upgraded to 256x256 / BK=64 / 8-wave
// deep-pipelined structure (T2 LDS swizzle + T3/T4 counted-vmcnt double
// buffer + T5 setprio + T1 XCD swizzle). Everything else = round-4 (passing).
//
// GEMMs: bf16 MFMA, 3-term hi/lo split (A*B ~= Ahi*Bhi + Alo*Bhi + Ahi*Blo).
// WKV linear recurrence: 3-pass chunked scan (L=64), exact w^L carry.
// Workspace: ws_size-adaptive batch chunking (nc in {1,2,4}).
// ============================================================================

typedef float  f32x4   __attribute__((ext_vector_type(4)));
typedef short  short8  __attribute__((ext_vector_type(8)));
typedef short  short4_ __attribute__((ext_vector_type(4)));
typedef __bf16 bf16x8  __attribute__((ext_vector_type(8)));

constexpr int kD   = 2048;
constexpr int kSeq = 4096;
constexpr int kBat = 4;
constexpr int kM   = kBat * kSeq;   // 16384 tokens
constexpr int kL   = 64;            // scan chunk length
constexpr int kC   = kSeq / kL;     // 64 chunks

// ---------------------------------------------------------------------------
// bf16 helpers (RNE)
// ---------------------------------------------------------------------------
__device__ __forceinline__ short f2bf(float f) {
  unsigned u = __builtin_bit_cast(unsigned, f);
  u += 0x7FFFu + ((u >> 16) & 1u);
  return (short)(u >> 16);
}
__device__ __forceinline__ float bf2f(short h) {
  unsigned u = ((unsigned)(unsigned short)h) << 16;
  return __builtin_bit_cast(float, u);
}
__device__ __forceinline__ void split_bf(float v, short& hi, short& lo) {
  hi = f2bf(v);
  lo = f2bf(v - bf2f(hi));
}

// ---------------------------------------------------------------------------
// block-wide reduction of 4 floats (256 threads = 4 waves), result broadcast
// ---------------------------------------------------------------------------
__device__ __forceinline__ f32x4 block_reduce4(f32x4 v) {
  #pragma unroll
  for (int off = 32; off > 0; off >>= 1) {
    v[0] += __shfl_down(v[0], off);
    v[1] += __shfl_down(v[1], off);
    v[2] += __shfl_down(v[2], off);
    v[3] += __shfl_down(v[3], off);
  }
  __shared__ float sh[4][4];
  const int wid = threadIdx.x >> 6, lane = threadIdx.x & 63;
  if (lane == 0) { sh[wid][0] = v[0]; sh[wid][1] = v[1]; sh[wid][2] = v[2]; sh[wid][3] = v[3]; }
  __syncthreads();
  #pragma unroll
  for (int i = 0; i < 4; ++i) v[i] = sh[0][i] + sh[1][i] + sh[2][i] + sh[3][i];
  return v;
}

// ---------------------------------------------------------------------------
// weight convert: fp32 W[K,N] -> bf16 hi/lo transposed [N,K]
// ---------------------------------------------------------------------------
__global__ __launch_bounds__(256) void wconvert_kernel(
    const float* __restrict__ W, short* __restrict__ hi, short* __restrict__ lo,
    int K, int N) {
  __shared__ float tile[32][33];
  const int tx = threadIdx.x & 31, ty = threadIdx.x >> 5;  // 32x8
  const int n0 = blockIdx.x * 32, k0 = blockIdx.y * 32;
  #pragma unroll
  for (int i = 0; i < 32; i += 8)
    tile[ty + i][tx] = W[(size_t)(k0 + ty + i) * N + (n0 + tx)];
  __syncthreads();
  #pragma unroll
  for (int i = 0; i < 32; i += 8) {
    float v = tile[tx][ty + i];           // = W[k0+tx][n0+ty+i]
    int n = n0 + ty + i, k = k0 + tx;
    short h, l; split_bf(v, h, l);
    hi[(size_t)n * K + k] = h;
    lo[(size_t)n * K + k] = l;
  }
}

// ---------------------------------------------------------------------------
// LN1 fused with token-shift mixing for r/k/v, writes hi/lo bf16 splits.
// ---------------------------------------------------------------------------
__global__ __launch_bounds__(256) void ln1mix_kernel(
    const float* __restrict__ x, const float* __restrict__ w1, const float* __restrict__ b1,
    const float* __restrict__ tmr, const float* __restrict__ tmk, const float* __restrict__ tmv,
    short* __restrict__ mr_hi, short* __restrict__ mr_lo,
    short* __restrict__ mk_hi, short* __restrict__ mk_lo,
    short* __restrict__ mv_hi, short* __restrict__ mv_lo) {
  const int row = blockIdx.x;
  const int s = row & (kSeq - 1);
  const float* xs = x + (size_t)row * kD;
  const int t = threadIdx.x;
  f32x4 a[2];
  f32x4 p[2] = {};
  a[0] = *(const f32x4*)&xs[4 * t];
  a[1] = *(const f32x4*)&xs[1024 + 4 * t];
  if (s > 0) {
    p[0] = *(const f32x4*)&xs[4 * t - kD];
    p[1] = *(const f32x4*)&xs[1024 + 4 * t - kD];
  }
  f32x4 sums = {0.f, 0.f, 0.f, 0.f};
  #pragma unroll
  for (int g = 0; g < 2; ++g)
    #pragma unroll
    for (int j = 0; j < 4; ++j) {
      sums[0] += a[g][j]; sums[1] += a[g][j] * a[g][j];
      sums[2] += p[g][j]; sums[3] += p[g][j] * p[g][j];
    }
  sums = block_reduce4(sums);
  const float inv = 1.f / kD;
  const float ms = sums[0] * inv, vs = sums[1] * inv - ms * ms;
  const float mp = sums[2] * inv, vp = sums[3] * inv - mp * mp;
  const float rs = rsqrtf(vs + 1e-5f);
  const float rp = rsqrtf(vp + 1e-5f);
  #pragma unroll
  for (int g = 0; g < 2; ++g) {
    const int d0 = g * 1024 + 4 * t;
    short4_ rh, rl, kh, kl, vh, vl;
    #pragma unroll
    for (int j = 0; j < 4; ++j) {
      const int d = d0 + j;
      const float w = w1[d], bb = b1[d];
      const float h  = (a[g][j] - ms) * rs * w + bb;
      const float hp = (s > 0) ? (p[g][j] - mp) * rp * w + bb : 0.f;
      const float cr = tmr[d], ck = tmk[d], cv = tmv[d];
      short th, tl;
      split_bf(h * cr + hp * (1.f - cr), th, tl); rh[j] = th; rl[j] = tl;
      split_bf(h * ck + hp * (1.f - ck), th, tl); kh[j] = th; kl[j] = tl;
      split_bf(h * cv + hp * (1.f - cv), th, tl); vh[j] = th; vl[j] = tl;
    }
    const size_t o = (size_t)row * kD + d0;
    *(short4_*)&mr_hi[o] = rh; *(short4_*)&mr_lo[o] = rl;
    *(short4_*)&mk_hi[o] = kh; *(short4_*)&mk_lo[o] = kl;
    *(short4_*)&mv_hi[o] = vh; *(short4_*)&mv_lo[o] = vl;
  }
}

// ---------------------------------------------------------------------------
// LN2 + channel-mix token-shift (single coefficient), hi/lo output
// ---------------------------------------------------------------------------
__global__ __launch_bounds__(256) void lnmix_kernel(
    const float* __restrict__ xb, const float* __restrict__ w, const float* __restrict__ b,
    const float* __restrict__ coeff,
    short* __restrict__ mhi, short* __restrict__ mlo) {
  const int row = blockIdx.x;
  const int s = row & (kSeq - 1);
  const float* xs = xb + (size_t)row * kD;
  const int t = threadIdx.x;
  f32x4 a[2];
  f32x4 p[2] = {};
  a[0] = *(const f32x4*)&xs[4 * t];
  a[1] = *(const f32x4*)&xs[1024 + 4 * t];
  if (s > 0) {
    p[0] = *(const f32x4*)&xs[4 * t - kD];
    p[1] = *(const f32x4*)&xs[1024 + 4 * t - kD];
  }
  f32x4 sums = {0.f, 0.f, 0.f, 0.f};
  #pragma unroll
  for (int g = 0; g < 2; ++g)
    #pragma unroll
    for (int j = 0; j < 4; ++j) {
      sums[0] += a[g][j]; sums[1] += a[g][j] * a[g][j];
      sums[2] += p[g][j]; sums[3] += p[g][j] * p[g][j];
    }
  sums = block_reduce4(sums);
  const float inv = 1.f / kD;
  const float ms = sums[0] * inv, vs = sums[1] * inv - ms * ms;
  const float mp = sums[2] * inv, vp = sums[3] * inv - mp * mp;
  const float rs = rsqrtf(vs + 1e-5f);
  const float rp = rsqrtf(vp + 1e-5f);
  #pragma unroll
  for (int g = 0; g < 2; ++g) {
    const int d0 = g * 1024 + 4 * t;
    short4_ mh, ml;
    #pragma unroll
    for (int j = 0; j < 4; ++j) {
      const int d = d0 + j;
      const float ww = w[d], bb = b[d];
      const float h  = (a[g][j] - ms) * rs * ww + bb;
      const float hp = (s > 0) ? (p[g][j] - mp) * rp * ww + bb : 0.f;
      const float c = coeff[d];
      short th, tl;
      split_bf(h * c + hp * (1.f - c), th, tl);
      mh[j] = th; ml[j] = tl;
    }
    const size_t o = (size_t)row * kD + d0;
    *(short4_*)&mhi[o] = mh; *(short4_*)&mlo[o] = ml;
  }
}

// ---------------------------------------------------------------------------
// WKV chunked scan over one batch-chunk
// ---------------------------------------------------------------------------
__global__ __launch_bounds__(256) void scan1_kernel(
    const float* __restrict__ kv, const float* __restrict__ td,
    float* __restrict__ chunk_end) {
  const int idx = blockIdx.x * 256 + threadIdx.x;          // (b_local,c,d)
  const int d = idx & (kD - 1);
  const int c = (idx >> 11) & (kC - 1);
  const int b = idx >> 17;
  const float w = expf(-expf(td[d]));
  const float* p = kv + ((size_t)b * kSeq + (size_t)c * kL) * kD + d;
  float st = 0.f;
  #pragma unroll 4
  for (int i = 0; i < kL; ++i) st = st * w + p[(size_t)i * kD];
  chunk_end[idx] = st;
}

__global__ __launch_bounds__(256) void scan2_kernel(
    const float* __restrict__ chunk_end, const float* __restrict__ td,
    float* __restrict__ carry) {
  const int idx = blockIdx.x * 256 + threadIdx.x;          // (b_local,d)
  const int d = idx & (kD - 1);
  const int b = idx >> 11;
  const float wL = expf(-expf(td[d]) * (float)kL);         // w^L exactly
  float c = 0.f;
  for (int i = 0; i < kC; ++i) {
    const size_t o = ((size_t)b * kC + i) * kD + d;
    carry[o] = c;
    c = c * wL + chunk_end[o];
  }
}

__global__ __launch_bounds__(256) void scan3_kernel(
    const float* __restrict__ kv, const float* __restrict__ carry,
    const float* __restrict__ rsig, const float* __restrict__ td,
    const float* __restrict__ tf,
    short* __restrict__ whi, short* __restrict__ wlo) {
  const int idx = blockIdx.x * 256 + threadIdx.x;          // (b_local,c,d)
  const int d = idx & (kD - 1);
  const int c = (idx >> 11) & (kC - 1);
  const int b = idx >> 17;
  const float w = expf(-expf(td[d]));
  float st = carry[idx];
  const size_t base = ((size_t)b * kSeq + (size_t)c * kL) * kD + d;
  const float bonus = (c == 0) ? expf(tf[d]) : 0.f;
  #pragma unroll 4
  for (int i = 0; i < kL; ++i) {
    const size_t o = base + (size_t)i * kD;
    const float kvv = kv[o];
    st = st * w + kvv;
    float out = rsig[o] * st;
    if (c == 0 && i == 0) out += rsig[o] * bonus * kvv;    // t==0 bonus
    short h, l; split_bf(out, h, l);
    whi[o] = h; wlo[o] = l;
  }
}

// ---------------------------------------------------------------------------
// 256x256 deep-pipelined 3-term split-bf16 GEMM.
//  - 8 waves (2M x 4N), per-wave 128x64 output, 16x16x32 MFMA.
//  - BK=64 K-tiles; logical K' = 3K via hi/lo pointer select per K-tile.
//  - LDS 128 KB double buffer; counted s_waitcnt vmcnt(8) (never 0 mid-loop).
//  - T2 swizzle: linear LDS dest, XOR-permuted GLOBAL source granule,
//    matching XOR on ds_read granule (rule 21 both-sides involution).
//  - raw s_barrier phases + lgkmcnt(0)+sched_barrier(0) (rule 18) + setprio.
// ---------------------------------------------------------------------------
constexpr int EPI_SIG = 0, EPI_NONE = 1, EPI_MULK = 2, EPI_ADDX = 3,
              EPI_SQ = 4, EPI_ACC0 = 5, EPI_ACC1 = 6, EPI_FINAL = 7;

#define AS1 __attribute__((address_space(1)))
#define AS3 __attribute__((address_space(3)))

template <int EPI>
__global__ __launch_bounds__(512, 2) void gemm256_kernel(
    const short* __restrict__ Ahi, const short* __restrict__ Alo,
    const short* __restrict__ Bhi, const short* __restrict__ Blo,
    int M, int N, int K, int ldb,
    float* __restrict__ outF,
    const float* __restrict__ aux1, const float* __restrict__ aux2,
    short* __restrict__ outHi, short* __restrict__ outLo) {
  __shared__ __align__(16) short As[2][256 * 64];   // 64 KB
  __shared__ __align__(16) short Bs[2][256 * 64];   // 64 KB
  const int tid = threadIdx.x;
  const int lane = tid & 63, wid = tid >> 6;        // 8 waves
  const int wr = wid >> 2, wc = wid & 3;            // 2 x 4 wave grid

  // T1: XCD-aware bijective swizzle (nwg % 8 == 0 for all grids here).
  const int nwg = gridDim.x * gridDim.y;
  const int bid = blockIdx.y * gridDim.x + blockIdx.x;
  const int sw  = (bid & 7) * (nwg >> 3) + (bid >> 3);
  const int mBase = (sw / gridDim.x) * 256;
  const int nBase = (sw % gridDim.x) * 256;

  // staging geometry: each gload covers 8 rows x 64 cols (1 KB);
  // per wave per K-tile: 4 A-gloads + 4 B-gloads covering rows [wid*32,+32).
  const int srow = lane >> 3;                       // row within 8-row chunk
  const int sgr  = (lane & 7) ^ srow;               // swizzled source granule
  const int tpt  = K >> 6;                          // K-tiles per third
  const int ktiles = 3 * tpt;

  // fragment geometry
  const int frow = lane & 15;
  const int quad = lane >> 4;                       // 0..3

  f32x4 acc[8][4] = {};

  auto STAGE = [&](int t) {
    const int buf = t & 1;
    const int third = t / tpt;
    const int kk = (t - third * tpt) << 6;
    const short* __restrict__ Ab = (third == 1) ? Alo : Ahi;
    const short* __restrict__ Bb = (third == 2) ? Blo : Bhi;
    const int r0 = wid * 32;
    #pragma unroll
    for (int i = 0; i < 4; ++i) {
      const int rr = r0 + i * 8;
      const short* g = Ab + (size_t)(mBase + rr + srow) * K + kk + sgr * 8;
      __builtin_amdgcn_global_load_lds(
          (const AS1 void*)g, (AS3 void*)&As[buf][rr * 64], 16, 0, 0);
    }
    #pragma unroll
    for (int i = 0; i < 4; ++i) {
      const int rr = r0 + i * 8;
      const short* g = Bb + (size_t)(nBase + rr + srow) * ldb + kk + sgr * 8;
      __builtin_amdgcn_global_load_lds(
          (const AS1 void*)g, (AS3 void*)&Bs[buf][rr * 64], 16, 0, 0);
    }
  };

  // prologue: two K-tiles in flight
  STAGE(0);
  STAGE(1);

  for (int t = 0; t < ktiles; ++t) {
    const int buf = t & 1;
    // counted wait: S(t+1)'s 8 loads stay in flight; in-order retirement
    // means <=8 outstanding  <=>  S(t) fully landed.
    if (t + 1 < ktiles) asm volatile("s_waitcnt vmcnt(8)");
    else                asm volatile("s_waitcnt vmcnt(0)");
    __builtin_amdgcn_s_barrier();      // all waves' S(t) portions visible
    asm volatile("" ::: "memory");

    // B fragments: reused across all 4 phases (4 ni x 2 ks = 8 reads)
    short8 bfr[4][2];
    #pragma unroll
    for (int ni = 0; ni < 4; ++ni)
      #pragma unroll
      for (int ks = 0; ks < 2; ++ks) {
        const int row = wc * 64 + ni * 16 + frow;
        const int g = ks * 4 + quad;
        bfr[ni][ks] = *(const short8*)&Bs[buf][row * 64 + ((g ^ (row & 7)) << 3)];
      }

    #pragma unroll
    for (int p = 0; p < 4; ++p) {
      short8 afr[2][2];                 // mi = 2p, 2p+1
      #pragma unroll
      for (int j = 0; j < 2; ++j)
        #pragma unroll
        for (int ks = 0; ks < 2; ++ks) {
          const int row = wr * 128 + (2 * p + j) * 16 + frow;
          const int g = ks * 4 + quad;
          afr[j][ks] = *(const short8*)&As[buf][row * 64 + ((g ^ (row & 7)) << 3)];
        }
      asm volatile("" ::: "memory");
      __builtin_amdgcn_s_barrier();     // phase alignment across waves
      asm volatile("s_waitcnt lgkmcnt(0)");
      __builtin_amdgcn_sched_barrier(0);
      __builtin_amdgcn_s_setprio(1);
      #pragma unroll
      for (int j = 0; j < 2; ++j)
        #pragma unroll
        for (int ni = 0; ni < 4; ++ni)
          #pragma unroll
          for (int ks = 0; ks < 2; ++ks)
            acc[2 * p + j][ni] = __builtin_amdgcn_mfma_f32_16x16x32_bf16(
                __builtin_bit_cast(bf16x8, afr[j][ks]),
                __builtin_bit_cast(bf16x8, bfr[ni][ks]),
                acc[2 * p + j][ni], 0, 0, 0);
      __builtin_amdgcn_s_setprio(0);
      __builtin_amdgcn_sched_barrier(0);
      asm volatile("" ::: "memory");
      __builtin_amdgcn_s_barrier();     // all waves done with this phase
    }
    // buf[t&1] fully read by ALL waves -> safe to overwrite with S(t+2)
    if (t + 2 < ktiles) STAGE(t + 2);
  }

  // epilogue: D[row=(quad*4+r), col=frow] per 16x16 fragment
  #pragma unroll
  for (int mi = 0; mi < 8; ++mi) {
    #pragma unroll
    for (int ni = 0; ni < 4; ++ni) {
      const int gn = nBase + wc * 64 + ni * 16 + frow;
      #pragma unroll
      for (int r = 0; r < 4; ++r) {
        const int gm = mBase + wr * 128 + mi * 16 + quad * 4 + r;
        const size_t idx = (size_t)gm * N + gn;
        const float v = acc[mi][ni][r];
        if constexpr (EPI == EPI_SIG) {
          outF[idx] = 1.f / (1.f + expf(-v));
        } else if constexpr (EPI == EPI_NONE) {
          outF[idx] = v;
        } else if constexpr (EPI == EPI_MULK) {
          outF[idx] = v * aux1[idx];
        } else if constexpr (EPI == EPI_ADDX) {
          outF[idx] = v + aux1[idx];
        } else if constexpr (EPI == EPI_SQ) {
          const float q = v * v;        // relu(square(z)) == z^2
          short h, l; split_bf(q, h, l);
          outHi[idx] = h; outLo[idx] = l;
        } else if constexpr (EPI == EPI_ACC0) {
          outF[idx] = v;                // first K-chunk of Wcv
        } else if constexpr (EPI == EPI_ACC1) {
          outF[idx] += v;               // middle K-chunk
        } else {                        // EPI_FINAL
          outF[idx] = aux1[idx] + aux2[idx] * (outF[idx] + v);
        }
      }
    }
  }
}

// ---------------------------------------------------------------------------
// launch
// ---------------------------------------------------------------------------
extern "C" void kernel_launch(void* const* d_in, const int* in_sizes, int n_in,
                              void* d_out, int out_size, void* d_ws, size_t ws_size,
                              hipStream_t stream) {
  const float* x   = (const float*)d_in[0];
  const float* n1w = (const float*)d_in[1];
  const float* n1b = (const float*)d_in[2];
  const float* n2w = (const float*)d_in[3];
  const float* n2b = (const float*)d_in[4];
  const float* td  = (const float*)d_in[5];
  const float* tf  = (const float*)d_in[6];
  const float* Wr  = (const float*)d_in[7];
  const float* Wk  = (const float*)d_in[8];
  const float* Wv  = (const float*)d_in[9];
  const float* Wo  = (const float*)d_in[10];
  const float* tmr = (const float*)d_in[11];
  const float* tmk = (const float*)d_in[12];
  const float* tmv = (const float*)d_in[13];
  const float* Wcr = (const float*)d_in[14];
  const float* Wck = (const float*)d_in[15];
  const float* Wcv = (const float*)d_in[16];
  const float* cm  = (const float*)d_in[17];
  float* out = (float*)d_out;

  const size_t D2 = (size_t)kD * kD;
  const size_t D3 = (size_t)kD * (3 * kD);
  const size_t wbytes = (10 * D2 + 4 * D3) * sizeof(short);  // 184,549,376 B

  auto need = [&](int nc_) -> size_t {
    const size_t Mc_ = (size_t)kM / nc_;
    const size_t scanb = 2 * ((size_t)(kBat / nc_) * kC * kD) * sizeof(float);
    return wbytes + scanb + 4 * (Mc_ * kD * sizeof(float));
  };
  int nc = 4;
  if (ws_size >= need(1)) nc = 1;
  else if (ws_size >= need(2)) nc = 2;

  const size_t Mc = (size_t)kM / nc;  // tokens per chunk (multiple of kSeq)
  const int Bc = kBat / nc;           // batches per chunk

  // ---- workspace arena ----
  short* wp = (short*)d_ws;
  short* WrT_hi  = wp; wp += D2;  short* WrT_lo  = wp; wp += D2;
  short* WkT_hi  = wp; wp += D2;  short* WkT_lo  = wp; wp += D2;
  short* WvT_hi  = wp; wp += D2;  short* WvT_lo  = wp; wp += D2;
  short* WoT_hi  = wp; wp += D2;  short* WoT_lo  = wp; wp += D2;
  short* WcrT_hi = wp; wp += D2;  short* WcrT_lo = wp; wp += D2;
  short* WckT_hi = wp; wp += D3;  short* WckT_lo = wp; wp += D3;
  short* WcvT_hi = wp; wp += D3;  short* WcvT_lo = wp; wp += D3;
  float* chunk_end = (float*)wp;                       // Bc*kC*kD floats
  float* carry = chunk_end + (size_t)Bc * kC * kD;
  float* slotA = carry + (size_t)Bc * kC * kD;         // 4 slots, Mc*kD f32
  float* slotB = slotA + Mc * kD;
  float* slotC = slotB + Mc * kD;
  float* slotD = slotC + Mc * kD;

  const dim3 blk(256);
  const dim3 gblk(512);

  // 1) weight conversion
  wconvert_kernel<<<dim3(kD / 32, kD / 32), blk, 0, stream>>>(Wr,  WrT_hi,  WrT_lo,  kD, kD);
  wconvert_kernel<<<dim3(kD / 32, kD / 32), blk, 0, stream>>>(Wk,  WkT_hi,  WkT_lo,  kD, kD);
  wconvert_kernel<<<dim3(kD / 32, kD / 32), blk, 0, stream>>>(Wv,  WvT_hi,  WvT_lo,  kD, kD);
  wconvert_kernel<<<dim3(kD / 32, kD / 32), blk, 0, stream>>>(Wo,  WoT_hi,  WoT_lo,  kD, kD);
  wconvert_kernel<<<dim3(kD / 32, kD / 32), blk, 0, stream>>>(Wcr, WcrT_hi, WcrT_lo, kD, kD);
  wconvert_kernel<<<dim3(3 * kD / 32, kD / 32), blk, 0, stream>>>(Wck, WckT_hi, WckT_lo, kD, 3 * kD);
  wconvert_kernel<<<dim3(kD / 32, 3 * kD / 32), blk, 0, stream>>>(Wcv, WcvT_hi, WcvT_lo, 3 * kD, kD);

  for (int c = 0; c < nc; ++c) {
    const float* xc = x + (size_t)c * Mc * kD;
    float* outc = out + (size_t)c * Mc * kD;

    short* mr_hi = (short*)slotA; short* mr_lo = mr_hi + Mc * kD;
    short* mk_hi = (short*)slotB; short* mk_lo = mk_hi + Mc * kD;
    short* mv_hi = (short*)slotC; short* mv_lo = mv_hi + Mc * kD;
    float* r_sig = slotD;
    float* kbuf  = slotA;                                             // mr dead
    float* kvbuf = slotB;                                             // mk dead
    short* wkv_hi = (short*)slotC; short* wkv_lo = wkv_hi + Mc * kD;  // mv dead
    float* x1 = slotA;                                                // kbuf dead
    short* m2_hi = (short*)slotD; short* m2_lo = m2_hi + Mc * kD;     // r_sig dead
    float* r_cm = slotB;                                              // kvbuf dead
    short* kcm_hi = (short*)slotC; short* kcm_lo = kcm_hi + Mc * kD;  // wkv dead

    const dim3 g256(kD / 256, Mc / 256);   // (8, Mc/256) -> nwg % 8 == 0

    // 2) LN1 + token-shift mixes (one pass, three outputs)
    ln1mix_kernel<<<Mc, blk, 0, stream>>>(xc, n1w, n1b, tmr, tmk, tmv,
                                          mr_hi, mr_lo, mk_hi, mk_lo, mv_hi, mv_lo);

    // 3) r/k/v GEMMs (r fused sigmoid; v fused *k -> kv)
    gemm256_kernel<EPI_SIG><<<g256, gblk, 0, stream>>>(
        mr_hi, mr_lo, WrT_hi, WrT_lo, (int)Mc, kD, kD, kD,
        r_sig, nullptr, nullptr, nullptr, nullptr);
    gemm256_kernel<EPI_NONE><<<g256, gblk, 0, stream>>>(
        mk_hi, mk_lo, WkT_hi, WkT_lo, (int)Mc, kD, kD, kD,
        kbuf, nullptr, nullptr, nullptr, nullptr);
    gemm256_kernel<EPI_MULK><<<g256, gblk, 0, stream>>>(
        mv_hi, mv_lo, WvT_hi, WvT_lo, (int)Mc, kD, kD, kD,
        kvbuf, kbuf, nullptr, nullptr, nullptr);

    // 4) WKV scan (fused sigmoid(r)*state, t==0 bonus, bf16 split)
    scan1_kernel<<<(Bc * kC * kD) / 256, blk, 0, stream>>>(kvbuf, td, chunk_end);
    scan2_kernel<<<(Bc * kD) / 256, blk, 0, stream>>>(chunk_end, td, carry);
    scan3_kernel<<<(Bc * kC * kD) / 256, blk, 0, stream>>>(kvbuf, carry, r_sig, td, tf,
                                                           wkv_hi, wkv_lo);

    // 5) output projection + residual
    gemm256_kernel<EPI_ADDX><<<g256, gblk, 0, stream>>>(
        wkv_hi, wkv_lo, WoT_hi, WoT_lo, (int)Mc, kD, kD, kD,
        x1, xc, nullptr, nullptr, nullptr);

    // 6) channel mixing
    lnmix_kernel<<<Mc, blk, 0, stream>>>(x1, n2w, n2b, cm, m2_hi, m2_lo);
    gemm256_kernel<EPI_SIG><<<g256, gblk, 0, stream>>>(
        m2_hi, m2_lo, WcrT_hi, WcrT_lo, (int)Mc, kD, kD, kD,
        r_cm, nullptr, nullptr, nullptr, nullptr);

    // Wck/Wcv in 3 K-chunks of 2048; partials accumulate into outc
    for (int j = 0; j < 3; ++j) {
      gemm256_kernel<EPI_SQ><<<g256, gblk, 0, stream>>>(
          m2_hi, m2_lo, WckT_hi + (size_t)j * kD * kD, WckT_lo + (size_t)j * kD * kD,
          (int)Mc, kD, kD, kD, nullptr, nullptr, nullptr, kcm_hi, kcm_lo);
      if (j == 0)
        gemm256_kernel<EPI_ACC0><<<g256, gblk, 0, stream>>>(
            kcm_hi, kcm_lo, WcvT_hi + (size_t)j * kD, WcvT_lo + (size_t)j * kD,
            (int)Mc, kD, kD, 3 * kD, outc, nullptr, nullptr, nullptr, nullptr);
      else if (j == 1)
        gemm256_kernel<EPI_ACC1><<<g256, gblk, 0, stream>>>(
            kcm_hi, kcm_lo, WcvT_hi + (size_t)j * kD, WcvT_lo + (size_t)j * kD,
            (int)Mc, kD, kD, 3 * kD, outc, nullptr, nullptr, nullptr, nullptr);
      else
        gemm256_kernel<EPI_FINAL><<<g256, gblk, 0, stream>>>(
            kcm_hi, kcm_lo, WcvT_hi + (size_t)j * kD, WcvT_lo + (size_t)j * kD,
            (int)Mc, kD, kD, 3 * kD, outc, x1, r_cm, nullptr, nullptr);
    }
  }
}